// Round 2
// 70.341 us; speedup vs baseline: 1.0339x; 1.0339x over previous
//
#include <hip/hip_runtime.h>

// Problem constants
constexpr int I_SAMPLES = 32768;
constexpr int K_WIDTH   = 32;
constexpr int NNODES    = 193;     // 64*3 + 1
constexpr int N_ELEM    = 64;
constexpr int IK        = I_SAMPLES * K_WIDTH;

// d_ws layout:
//   W1: float4[4][64][32]   -> W1[((j*64+e)*32)+k] = {W_in[k][3e+p][j]}p=0..3   (128 KB)
//   W2: float4[64][32]      -> W2[e*32+k]          = {W_out[k][3e+p]}p=0..3     ( 32 KB)
constexpr int W1_N = 4 * N_ELEM * K_WIDTH;   // 8192 float4
constexpr int W2_N = N_ELEM * K_WIDTH;       // 2048 float4

__global__ __launch_bounds__(256) void prep_kernel(
    const float* __restrict__ W_in,   // (32, 193, 4)
    const float* __restrict__ W_out,  // (32, 193)
    float4* __restrict__ W1,
    float4* __restrict__ W2)
{
    const int t = blockIdx.x * blockDim.x + threadIdx.x;
    if (t < W1_N) {
        const int k = t & 31;
        const int e = (t >> 5) & 63;
        const int j = t >> 11;                 // 0..3
        const int base = (k * NNODES + 3 * e) * 4 + j;
        float4 v;
        v.x = W_in[base + 0 * 4];
        v.y = W_in[base + 1 * 4];
        v.z = W_in[base + 2 * 4];
        v.w = W_in[base + 3 * 4];
        W1[t] = v;
    } else if (t < W1_N + W2_N) {
        const int u = t - W1_N;
        const int k = u & 31;
        const int e = u >> 5;
        const int base = k * NNODES + 3 * e;
        float4 v;
        v.x = W_out[base + 0];
        v.y = W_out[base + 1];
        v.z = W_out[base + 2];
        v.w = W_out[base + 3];
        W2[u] = v;
    }
}

// One thread per (i, c); c = tid & 7, k = c + 8q (q = 0..3).
// The i-dependent element transforms and Lagrange basis/derivative
// polynomials are computed ONCE per thread and amortized over 4 widths
// (was recomputed per-k before -> ~2.2x fewer VALU ops per output).
// W1 reads stay lane-contiguous: for fixed (j,q), lanes 0..7 load
// consecutive float4s (128 B segments), L1/L2-resident.
__global__ __launch_bounds__(256) void kann_kernel(
    const float* __restrict__ x,      // (I, 4)
    const float4* __restrict__ W1,
    const float4* __restrict__ W2,
    float* __restrict__ out)          // (4, I, 32) flat
{
    const int tid = blockIdx.x * blockDim.x + threadIdx.x;  // 0 .. I*8-1
    const int c = tid & 7;
    const int i = tid >> 3;

    const float4 xv = reinterpret_cast<const float4*>(x)[i];
    const float xj[4] = {xv.x, xv.y, xv.z, xv.w};

    // Cubic Lagrange basis on nodes {-1,-1/3,1/3,1}, monomial (exact) coeffs.
    const float C3[4] = {-0.5625f,  1.6875f, -1.6875f,  0.5625f};
    const float C2[4] = { 0.5625f, -0.5625f, -0.5625f,  0.5625f};
    const float C1[4] = { 0.0625f, -1.6875f,  1.6875f, -0.0625f};
    const float C0[4] = {-0.0625f,  0.5625f,  0.5625f, -0.0625f};

    float tacc[4] = {0.f, 0.f, 0.f, 0.f};
    float dta[4]  = {0.f, 0.f, 0.f, 0.f};
    float dda[4]  = {0.f, 0.f, 0.f, 0.f};

    #pragma unroll
    for (int j = 0; j < 4; ++j) {
        // inner transform, domain [-1,1] (mirror reference fp32 op order)
        const float xs = (192.0f * (xj[j] + 1.0f)) / 2.0f;
        float ide = floorf(xs / 3.0f);
        ide = fminf(fmaxf(ide, 0.0f), 63.0f);
        const int e  = (int)ide;
        const int nl = 3 * e;
        const float xr = (2.0f * (xs - (float)nl)) / 3.0f - 1.0f;

        // basis + derivatives: computed once, shared by the 4 widths
        float phi[4], dph[4], ddp[4];
        #pragma unroll
        for (int p = 0; p < 4; ++p) {
            phi[p] = ((C3[p] * xr + C2[p]) * xr + C1[p]) * xr + C0[p];
            dph[p] = (3.0f * C3[p] * xr + 2.0f * C2[p]) * xr + C1[p];
            ddp[p] = 6.0f * C3[p] * xr + 2.0f * C2[p];
        }

        const float4* row = W1 + (j * N_ELEM + e) * K_WIDTH + c;
        #pragma unroll
        for (int q = 0; q < 4; ++q) {
            const float4 w = row[8 * q];        // lanes 0..7 contiguous
            const float wv[4] = {w.x, w.y, w.z, w.w};
            #pragma unroll
            for (int p = 0; p < 4; ++p) {
                tacc[q] += wv[p] * phi[p];
                dta[q]  += wv[p] * dph[p];
                dda[q]  += wv[p] * ddp[p];
            }
        }
    }

    #pragma unroll
    for (int q = 0; q < 4; ++q) {
        const float t   = tacc[q];
        const float dt  = dta[q] * 64.0f;       // delta_in = 1/64 exactly
        const float ddt = dda[q] * 4096.0f;

        // outer transform, domain [-3,3]
        const float xs2 = (192.0f * (t + 3.0f)) / 6.0f;
        float id2 = floorf(xs2 / 3.0f);
        id2 = fminf(fmaxf(id2, 0.0f), 63.0f);
        const int e2  = (int)id2;
        const int nl2 = 3 * e2;
        const float xr2 = (2.0f * (xs2 - (float)nl2)) / 3.0f - 1.0f;

        const int k = c + 8 * q;
        const float4 w2 = W2[e2 * K_WIDTH + k];
        const float w2v[4] = {w2.x, w2.y, w2.z, w2.w};
        float y = 0.f;
        #pragma unroll
        for (int p = 0; p < 4; ++p) {
            const float phi2 = ((C3[p] * xr2 + C2[p]) * xr2 + C1[p]) * xr2 + C0[p];
            y += w2v[p] * phi2;
        }

        const int o = i * K_WIDTH + k;
        out[o]          = y;
        out[IK + o]     = t;
        out[2 * IK + o] = dt;
        out[3 * IK + o] = ddt;
    }
}

extern "C" void kernel_launch(void* const* d_in, const int* in_sizes, int n_in,
                              void* d_out, int out_size, void* d_ws, size_t ws_size,
                              hipStream_t stream) {
    const float* x     = (const float*)d_in[0];
    const float* W_in  = (const float*)d_in[1];
    const float* W_out = (const float*)d_in[2];
    float* out = (float*)d_out;

    float4* W1 = (float4*)d_ws;
    float4* W2 = W1 + W1_N;

    prep_kernel<<<(W1_N + W2_N + 255) / 256, 256, 0, stream>>>(W_in, W_out, W1, W2);
    // I*8 threads (8 threads per sample, each producing 4 widths)
    kann_kernel<<<(I_SAMPLES * 8) / 256, 256, 0, stream>>>(x, W1, W2, out);
}

// Round 3
// 68.856 us; speedup vs baseline: 1.0562x; 1.0216x over previous
//
#include <hip/hip_runtime.h>

// Problem constants
constexpr int I_SAMPLES = 32768;
constexpr int K_WIDTH   = 32;
constexpr int NNODES    = 193;     // 64*3 + 1
constexpr int N_ELEM    = 64;
constexpr int IK        = I_SAMPLES * K_WIDTH;

// Fused single-dispatch kernel.
// Grid: 512 blocks x 512 threads. blockIdx bit0 = khalf (which 16 widths),
// blockIdx>>1 = sample chunk (128 samples). Thread = (sample, c); it produces
// the 4 consecutive widths k = khalf*16 + 4c + m, m=0..3.
//
// Each block stages its 16-width slice of W_in into exactly 64 KB of STATIC
// shared memory (no dynamic-LDS opt-in, no runtime attribute calls):
//   row (j,e) = 64 dwords = 16 float4 slots; slot for (kl,p) is
//   float4 index (kl ^ (e&7)), dword p  -- XOR swizzle so a wave's 16
//   samples (distinct e) spread across banks instead of colliding 16-way.
//   The XOR touches float4-index bits only, so the per-thread p-quad stays
//   a contiguous aligned 16B group -> ds_read_b128 in the main loop.
__global__ __launch_bounds__(512, 4) void kann_fused_kernel(
    const float* __restrict__ x,      // (I, 4)
    const float* __restrict__ W_in,   // (32, 193, 4)
    const float* __restrict__ W_out,  // (32, 193)
    float* __restrict__ out)          // (4, I, 32) flat
{
    __shared__ float lds_f[4 * 64 * 64];                 // 65536 B exactly
    float4* lds4 = reinterpret_cast<float4*>(lds_f);

    const int khalf = blockIdx.x & 1;
    const int sblk  = blockIdx.x >> 1;                   // 0..255

    // ---- stage the 16-width slice of W_in -> swizzled LDS ----
    // One float4 of W_in = all 4 j-components of node n for width k.
    {
        const float4* Win4 = reinterpret_cast<const float4*>(W_in)
                           + khalf * 16 * NNODES;
        for (int s4 = threadIdx.x; s4 < 16 * NNODES; s4 += 512) {
            const int kl = s4 / NNODES;                  // local width 0..15
            const int n  = s4 - kl * NNODES;             // node 0..192
            const float4 v = Win4[s4];
            const float vj[4] = {v.x, v.y, v.z, v.w};
            const int e  = n / 3;                        // candidate element
            const int t3 = n - 3 * e;                    // local node
            if (n < 192) {                               // (elem e, p = t3)
                const int w = (((kl ^ (e & 7)) << 2) + t3);
                #pragma unroll
                for (int j = 0; j < 4; ++j)
                    lds_f[(j * 64 + e) * 64 + w] = vj[j];
            }
            if (t3 == 0 && n > 0) {                      // boundary: (e-1, p=3)
                const int eb = e - 1;
                const int w = (((kl ^ (eb & 7)) << 2) + 3);
                #pragma unroll
                for (int j = 0; j < 4; ++j)
                    lds_f[(j * 64 + eb) * 64 + w] = vj[j];
            }
        }
    }
    __syncthreads();

    const int c  = threadIdx.x & 3;                      // k-quad within half
    const int il = threadIdx.x >> 2;                     // 0..127
    const int i  = sblk * 128 + il;                      // sample index

    const float4 xv = reinterpret_cast<const float4*>(x)[i];
    const float xj[4] = {xv.x, xv.y, xv.z, xv.w};

    // Cubic Lagrange basis on nodes {-1,-1/3,1/3,1}, monomial (exact) coeffs.
    const float C3[4] = {-0.5625f,  1.6875f, -1.6875f,  0.5625f};
    const float C2[4] = { 0.5625f, -0.5625f, -0.5625f,  0.5625f};
    const float C1[4] = { 0.0625f, -1.6875f,  1.6875f, -0.0625f};
    const float C0[4] = {-0.0625f,  0.5625f,  0.5625f, -0.0625f};

    float tacc[4] = {0.f, 0.f, 0.f, 0.f};
    float dta[4]  = {0.f, 0.f, 0.f, 0.f};
    float dda[4]  = {0.f, 0.f, 0.f, 0.f};

    #pragma unroll
    for (int j = 0; j < 4; ++j) {
        // inner transform, domain [-1,1] (mirror reference fp32 op order)
        const float xs = (192.0f * (xj[j] + 1.0f)) / 2.0f;
        float ide = floorf(xs / 3.0f);
        ide = fminf(fmaxf(ide, 0.0f), 63.0f);
        const int e  = (int)ide;
        const int nl = 3 * e;
        const float xr = (2.0f * (xs - (float)nl)) / 3.0f - 1.0f;

        // basis + derivatives: once per (i,j), shared by the 4 widths
        float phi[4], dph[4], ddp[4];
        #pragma unroll
        for (int p = 0; p < 4; ++p) {
            phi[p] = ((C3[p] * xr + C2[p]) * xr + C1[p]) * xr + C0[p];
            dph[p] = (3.0f * C3[p] * xr + 2.0f * C2[p]) * xr + C1[p];
            ddp[p] = 6.0f * C3[p] * xr + 2.0f * C2[p];
        }

        const float4* row4 = lds4 + (j * 64 + e) * 16;
        const int sw = e & 7;
        #pragma unroll
        for (int m = 0; m < 4; ++m) {
            const int kl = 4 * c + m;
            const float4 w = row4[kl ^ sw];              // ds_read_b128
            const float wv[4] = {w.x, w.y, w.z, w.w};
            #pragma unroll
            for (int p = 0; p < 4; ++p) {
                tacc[m] += wv[p] * phi[p];
                dta[m]  += wv[p] * dph[p];
                dda[m]  += wv[p] * ddp[p];
            }
        }
    }

    float yo[4], to[4], dto[4], ddto[4];
    #pragma unroll
    for (int m = 0; m < 4; ++m) {
        const float t   = tacc[m];
        const float dt  = dta[m] * 64.0f;                // delta_in = 1/64
        const float ddt = dda[m] * 4096.0f;

        // outer transform, domain [-3,3]
        const float xs2 = (192.0f * (t + 3.0f)) / 6.0f;
        float id2 = floorf(xs2 / 3.0f);
        id2 = fminf(fmaxf(id2, 0.0f), 63.0f);
        const int e2  = (int)id2;
        const int nl2 = 3 * e2;
        const float xr2 = (2.0f * (xs2 - (float)nl2)) / 3.0f - 1.0f;

        const int k = khalf * 16 + 4 * c + m;
        const float* w2 = W_out + k * NNODES + nl2;      // 24.7 KB, L2-resident
        float y = 0.f;
        #pragma unroll
        for (int p = 0; p < 4; ++p) {
            const float phi2 = ((C3[p] * xr2 + C2[p]) * xr2 + C1[p]) * xr2 + C0[p];
            y += w2[p] * phi2;
        }
        yo[m] = y; to[m] = t; dto[m] = dt; ddto[m] = ddt;
    }

    // k-quad is 4 consecutive widths -> one dwordx4 store per output plane.
    float4* out4 = reinterpret_cast<float4*>(out);
    const int ob = i * 8 + khalf * 4 + c;                // float4 idx in plane
    out4[ob]              = make_float4(yo[0],   yo[1],   yo[2],   yo[3]);
    out4[IK / 4 + ob]     = make_float4(to[0],   to[1],   to[2],   to[3]);
    out4[2 * IK / 4 + ob] = make_float4(dto[0],  dto[1],  dto[2],  dto[3]);
    out4[3 * IK / 4 + ob] = make_float4(ddto[0], ddto[1], ddto[2], ddto[3]);
}

extern "C" void kernel_launch(void* const* d_in, const int* in_sizes, int n_in,
                              void* d_out, int out_size, void* d_ws, size_t ws_size,
                              hipStream_t stream) {
    const float* x     = (const float*)d_in[0];
    const float* W_in  = (const float*)d_in[1];
    const float* W_out = (const float*)d_in[2];
    float* out = (float*)d_out;

    // Single fused dispatch; workspace unused; no runtime attribute calls.
    kann_fused_kernel<<<512, 512, 0, stream>>>(x, W_in, W_out, out);
}